// Round 7
// baseline (281.187 us; speedup 1.0000x reference)
//
#include <hip/hip_runtime.h>

// Batched thin QR (LAPACK sign convention) for 8192 x (256x16) fp32.
// One 64-lane wave per matrix; lane l owns rows {l, l+64, l+128, l+192}.
//
// Round-10: r8 base (champion) + early column-group stores.
//   r9 lesson: ANY second read of X pays real HBM (in+out > L3) -> reverted;
//   x stays resident (AGPR-parked; VGPR_Count excludes AGPRs, explaining the
//   "VGPR=60" readings). r8's remaining profile: VALU issue unsaturated, HBM
//   ~2 TB/s average but BURSTY: 1KB/lane load burst, compute, 1KB/lane store
//   burst -> the last occupancy batch's store drain (~67MB) is exposed.
//   Fix (zero added instructions): in Q = X R^{-1} forward elimination,
//   column k is final AND dead after step k; columns {4g..4g+3} of a row are
//   one aligned float4 -> store each 4-column group right when step 4g+3
//   completes. Same 16 dwordx4/thread, issued 10-40us earlier, overlapping
//   the solve's FMA chains; solve register pressure drops as columns retire.
//   Algorithm unchanged from r8 (verified): split-f16 MFMA Gram; chol(G_bot);
//   C=[X_top;U] mirrored; dual-column DPP Householder (LAPACK pivots/signs);
//   register forward elimination.

constexpr int BATCH = 8192;
constexpr int DROWS = 256;
constexpr int QC    = 16;

typedef _Float16 half8 __attribute__((ext_vector_type(8)));
typedef float    f32x4 __attribute__((ext_vector_type(4)));

__device__ __forceinline__ float rdlane(float v, int l) {
    return __int_as_float(__builtin_amdgcn_readlane(__float_as_int(v), l));
}

template <int CTRL>
__device__ __forceinline__ float dpp_add(float x) {
    int y = __builtin_amdgcn_update_dpp(0, __float_as_int(x), CTRL, 0xf, 0xf, true);
    return x + __int_as_float(y);
}

// Sum over lanes 0..31 (upper half may hold garbage) -> wave-uniform.
__device__ __forceinline__ float wave_sum32(float x) {
    x = dpp_add<0xB1>(x);   // quad_perm [1,0,3,2] : xor 1
    x = dpp_add<0x4E>(x);   // quad_perm [2,3,0,1] : xor 2
    x = dpp_add<0x141>(x);  // row_half_mirror     : 8-group sums
    x = dpp_add<0x140>(x);  // row_mirror          : 16-row sums
    x = dpp_add<0x142>(x);  // row_bcast15         : lanes16-31 = r0+r1
    return rdlane(x, 31);
}

// TWO independent sums with one chain: lanes0-31 -> .x, lanes32-63 -> .y.
__device__ __forceinline__ float2 dual_sum32(float x) {
    x = dpp_add<0xB1>(x);
    x = dpp_add<0x4E>(x);
    x = dpp_add<0x141>(x);
    x = dpp_add<0x140>(x);  // each 16-row holds its row sum
    x = dpp_add<0x142>(x);  // bcast15: lanes16-31 = r0+r1, lanes48-63 = r2+r3
    return make_float2(rdlane(x, 31), rdlane(x, 63));
}

__global__ __launch_bounds__(256) void qr_estore_r10(
    const float* __restrict__ in, float* __restrict__ out)
{
    const int lane = threadIdx.x & 63;
    const int wid  = threadIdx.x >> 6;
    const int b    = blockIdx.x * 4 + wid;

    // per-wave LDS: two u16 planes [16 cols][72 rows] (h, l), 4608 B/wave.
    // After the MFMA phase the same space is reused as the f32 G buffer.
    __shared__ __align__(16) char smem[4][2 * QC * 72 * 2];
    unsigned short* hp = reinterpret_cast<unsigned short*>(smem[wid]);
    unsigned short* lp = hp + QC * 72;

    const float4* __restrict__ A4 = (const float4*)(in  + (size_t)b * (DROWS * QC));
    float4*       __restrict__ O4 = (float4*)      (out + (size_t)b * (DROWS * QC));

    float x[4][QC];   // the matrix; becomes Q at the end

    // ---- load ----
#pragma unroll
    for (int s = 0; s < 4; ++s) {
        const int rr = s * 64 + lane;
#pragma unroll
        for (int q4 = 0; q4 < 4; ++q4) {
            float4 t = A4[rr * 4 + q4];
            x[s][q4*4+0] = t.x; x[s][q4*4+1] = t.y;
            x[s][q4*4+2] = t.z; x[s][q4*4+3] = t.w;
        }
    }

    // ---- G_bot via MFMA: stage split-f16 planes per 64-row slot, 8 K-chunks ----
    f32x4 accA = {0.f, 0.f, 0.f, 0.f};   // hh + ll chain
    f32x4 accB = {0.f, 0.f, 0.f, 0.f};   // hl + lh chain
    const int cm   = lane & 15;
    const int g4   = lane >> 4;
    const int fidx = cm * 72 + 8 * g4;   // u16 index of this lane's frag base

#pragma unroll
    for (int s = 0; s < 4; ++s) {
        // convert + scatter-write local row `lane` of this slot (mask rows<16)
#pragma unroll
        for (int c = 0; c < QC; ++c) {
            float v = x[s][c];
            if (s == 0) v = (lane < QC) ? 0.f : v;
            _Float16 hh = (_Float16)v;
            float     r = v - (float)hh;
            _Float16 ll = (_Float16)r;
            union { _Float16 f; unsigned short u; } ch, cl;
            ch.f = hh; cl.f = ll;
            hp[c * 72 + lane] = ch.u;
            lp[c * 72 + lane] = cl.u;
        }
        asm volatile("" ::: "memory");   // writes (u16) before frag reads (f16)
#pragma unroll
        for (int h = 0; h < 2; ++h) {
            const half8 fh = *reinterpret_cast<const half8*>(&hp[fidx + 32 * h]);
            const half8 fl = *reinterpret_cast<const half8*>(&lp[fidx + 32 * h]);
            accA = __builtin_amdgcn_mfma_f32_16x16x32_f16(fh, fh, accA, 0, 0, 0);
            accB = __builtin_amdgcn_mfma_f32_16x16x32_f16(fh, fl, accB, 0, 0, 0);
            accB = __builtin_amdgcn_mfma_f32_16x16x32_f16(fl, fh, accB, 0, 0, 0);
            accA = __builtin_amdgcn_mfma_f32_16x16x32_f16(fl, fl, accA, 0, 0, 0);
        }
        asm volatile("" ::: "memory");   // frag reads before next slot's writes
    }
    const f32x4 Gf = accA + accB;        // lane: G[4*g4+q][cm] (or transpose; G sym)

    // ---- scatter G to f32 buffer (pitch 20), gather row (lane&15) ----
    float* gbuf = reinterpret_cast<float*>(smem[wid]);
    asm volatile("" ::: "memory");
#pragma unroll
    for (int q = 0; q < 4; ++q) gbuf[(4 * g4 + q) * 20 + cm] = Gf[q];
    asm volatile("" ::: "memory");
    float g[QC];
#pragma unroll
    for (int k = 0; k < 4; ++k) {
        const f32x4 t = *reinterpret_cast<const f32x4*>(&gbuf[(lane & 15) * 20 + 4 * k]);
        g[4*k+0] = t[0]; g[4*k+1] = t[1]; g[4*k+2] = t[2]; g[4*k+3] = t[3];
    }

    const int li = lane - 16;   // cholesky row index for lanes 16..31

    // ---- Cholesky of G_bot (row i in lane 16+i; other lanes carry copies).
    //      Rows left unscaled; per-row scale rs = 1/sqrt(piv) applied at C build. ----
    float rs = 0.f;
#pragma unroll
    for (int k = 0; k < QC; ++k) {
        const float piv = rdlane(g[k], 16 + k);          // A^(k)[k][k]
        const float inv = __builtin_amdgcn_rcpf(piv);
        const float rsk = __builtin_amdgcn_rsqf(piv);
        rs = (li == k) ? rsk : rs;
        const float m = (li > k) ? g[k] * inv : 0.f;     // frozen rows -> no-op
#pragma unroll
        for (int j = k + 1; j < QC; ++j) {
            const float bj = rdlane(g[j], 16 + k);       // A^(k)[k][j] broadcast
            g[j] = fmaf(-m, bj, g[j]);
        }
    }

    // ---- C = [X_top ; U] built in lanes 0..31, then MIRRORED into 32..63 ----
    float c[QC];
#pragma unroll
    for (int t = 0; t < QC; ++t) {
        const float ub = (li <= t && li >= 0) ? g[t] * rs : 0.f;
        c[t] = (lane < QC) ? x[0][t] : ub;
    }
    const int baddr = (lane & 31) << 2;   // bpermute: lanes 32-63 pull lanes 0-31
#pragma unroll
    for (int t = 0; t < QC; ++t)
        c[t] = __int_as_float(__builtin_amdgcn_ds_bpermute(baddr, __float_as_int(c[t])));

    const bool hi  = (lane >= 32);
    const int  row = lane & 31;           // mirrored row index

    // column norms^2 of C (== column norms of X), two per chain
    float nrm2[QC];
#pragma unroll
    for (int m = 0; m < QC; m += 2) {
        const float pc = hi ? c[m + 1] : c[m];
        const float2 ss = dual_sum32(pc * pc);
        nrm2[m] = ss.x; nrm2[m + 1] = ss.y;
    }

    // ---- Householder on C (32x16), paired trailing columns ----
#pragma unroll
    for (int j = 0; j < QC; ++j) {
        const float piv   = rdlane(c[j], j);
        const float nrm   = sqrtf(nrm2[j]);
        const float alpha = -copysignf(nrm, piv);            // LAPACK dlarfg sign
        const float vtv   = 2.f * (nrm2[j] - alpha * piv);   // ||v||^2, no cancel
        const float beta  = 2.f * __builtin_amdgcn_rcpf(vtv);
        // reflector, mirrored across halves (c mirrored, conditions on row)
        const float v = (row < j) ? 0.f : ((row == j) ? piv - alpha : c[j]);
        int t = j + 1;
#pragma unroll
        for (; t + 1 < QC; t += 2) {
            const float pc = hi ? c[t + 1] : c[t];
            const float2 d = dual_sum32(v * pc);
            const float wb0 = beta * d.x;
            const float wb1 = beta * d.y;
            c[t]     = fmaf(-wb0, v, c[t]);
            c[t + 1] = fmaf(-wb1, v, c[t + 1]);
            const float rv0 = rdlane(c[t], j);               // R[j][t] frozen now
            const float rv1 = rdlane(c[t + 1], j);
            nrm2[t]     = fmaf(-rv0, rv0, nrm2[t]);
            nrm2[t + 1] = fmaf(-rv1, rv1, nrm2[t + 1]);
        }
        if (t < QC) {                                        // odd tail column
            const float d  = wave_sum32(v * c[t]);
            const float wb = beta * d;
            c[t] = fmaf(-wb, v, c[t]);
            const float rv = rdlane(c[t], j);
            nrm2[t] = fmaf(-rv, rv, nrm2[t]);
        }
        c[j] = (row == j) ? alpha : c[j];                    // R[j][j] (mirrored)
    }

    // ---- Q = X R^{-1}: forward elimination with EARLY column-group stores.
    //      Column k is finalized and dead after step k; after step 4g+3,
    //      columns 4g..4g+3 form one aligned float4 per row -> store then. ----
#pragma unroll
    for (int k = 0; k < QC; ++k) {
        const float rkk = rdlane(c[k], k);
        const float ikk = __builtin_amdgcn_rcpf(rkk);
        x[0][k] *= ikk; x[1][k] *= ikk; x[2][k] *= ikk; x[3][k] *= ikk;
#pragma unroll
        for (int t = k + 1; t < QC; ++t) {
            const float r = rdlane(c[t], k);                 // R[k][t]
            x[0][t] = fmaf(-r, x[0][k], x[0][t]);
            x[1][t] = fmaf(-r, x[1][k], x[1][t]);
            x[2][t] = fmaf(-r, x[2][k], x[2][t]);
            x[3][t] = fmaf(-r, x[3][k], x[3][t]);
        }
        if ((k & 3) == 3) {                                  // group 4g..4g+3 done
            const int kg = k >> 2;
#pragma unroll
            for (int s = 0; s < 4; ++s) {
                const int rr = s * 64 + lane;
                O4[rr * 4 + kg] = make_float4(x[s][4*kg+0], x[s][4*kg+1],
                                              x[s][4*kg+2], x[s][4*kg+3]);
            }
        }
    }
}

extern "C" void kernel_launch(void* const* d_in, const int* in_sizes, int n_in,
                              void* d_out, int out_size, void* d_ws, size_t ws_size,
                              hipStream_t stream) {
    const float* X = (const float*)d_in[0];
    float*       O = (float*)d_out;
    qr_estore_r10<<<BATCH / 4, 256, 0, stream>>>(X, O);
}

// Round 8
// 240.138 us; speedup vs baseline: 1.1709x; 1.1709x over previous
//
#include <hip/hip_runtime.h>

// Batched thin QR (LAPACK sign convention) for 8192 x (256x16) fp32.
// Round-11: TWO waves share one matrix (128-thread block) to halve the
// per-wave register footprint and raise residency ~2.8 -> ~5 waves/SIMD.
//   r10 lesson: early 16B-of-64B stores amplify writes 2.4x -> terminal
//   row-adjacent stores only. r1..r8 lesson: issue-count cuts are neutral;
//   the kernel is stall-bound and residency-capped by x[4][16].
//   Wave w of a pair owns 64-row slots {w, 2+w} (x[2][16] = 32 regs).
//   Gram: both waves co-stage split-f16 planes (stage t = k-rows 128t..+128,
//   wave w writes buffer rows w*64+lane), __syncthreads() write->read, both
//   waves run the same 16 MFMAs per stage (K-chunk order identical to r8 ->
//   bitwise-identical G/R/Q; absmax must stay exactly 0.0009765625).
//   X_top crosses waves via a small f32 LDS buffer. chol/C/HH duplicated
//   per wave (wave-local, no sync). Solve/store row-local per wave.

constexpr int BATCH = 8192;
constexpr int DROWS = 256;
constexpr int QC    = 16;
constexpr int PITCH = 136;   // u16 pitch per column in stage planes (17*16B)

typedef _Float16 half8 __attribute__((ext_vector_type(8)));
typedef float    f32x4 __attribute__((ext_vector_type(4)));

__device__ __forceinline__ float rdlane(float v, int l) {
    return __int_as_float(__builtin_amdgcn_readlane(__float_as_int(v), l));
}

template <int CTRL>
__device__ __forceinline__ float dpp_add(float x) {
    int y = __builtin_amdgcn_update_dpp(0, __float_as_int(x), CTRL, 0xf, 0xf, true);
    return x + __int_as_float(y);
}

// Sum over lanes 0..31 (upper half may hold garbage) -> wave-uniform.
__device__ __forceinline__ float wave_sum32(float x) {
    x = dpp_add<0xB1>(x);   // quad_perm [1,0,3,2] : xor 1
    x = dpp_add<0x4E>(x);   // quad_perm [2,3,0,1] : xor 2
    x = dpp_add<0x141>(x);  // row_half_mirror     : 8-group sums
    x = dpp_add<0x140>(x);  // row_mirror          : 16-row sums
    x = dpp_add<0x142>(x);  // row_bcast15         : lanes16-31 = r0+r1
    return rdlane(x, 31);
}

// TWO independent sums with one chain: lanes0-31 -> .x, lanes32-63 -> .y.
__device__ __forceinline__ float2 dual_sum32(float x) {
    x = dpp_add<0xB1>(x);
    x = dpp_add<0x4E>(x);
    x = dpp_add<0x141>(x);
    x = dpp_add<0x140>(x);  // each 16-row holds its row sum
    x = dpp_add<0x142>(x);  // bcast15: lanes16-31 = r0+r1, lanes48-63 = r2+r3
    return make_float2(rdlane(x, 31), rdlane(x, 63));
}

__global__ __launch_bounds__(128) void qr_pair_r11(
    const float* __restrict__ in, float* __restrict__ out)
{
    const int lane = threadIdx.x & 63;
    const int w    = threadIdx.x >> 6;    // wave index within the pair (0/1)
    const int b    = blockIdx.x;

    // LDS: split-f16 stage planes (2 x [16][PITCH] u16 = 8704 B), then
    // reused as the f32 G buffer; separate f32 X_top buffer (16x20 = 1280 B).
    __shared__ __align__(16) char smem[QC * PITCH * 2 * 2 + QC * 20 * 4];
    unsigned short* hp   = reinterpret_cast<unsigned short*>(smem);
    unsigned short* lp   = hp + QC * PITCH;
    float*          gbuf = reinterpret_cast<float*>(smem);              // reuse
    float*          xbuf = reinterpret_cast<float*>(smem + QC * PITCH * 2 * 2);

    const float4* __restrict__ A4 = (const float4*)(in  + (size_t)b * (DROWS * QC));
    float4*       __restrict__ O4 = (float4*)      (out + (size_t)b * (DROWS * QC));

    // wave w owns 64-row slots {w, 2+w}: global row = (2*s + w)*64 + lane
    float x[2][QC];
#pragma unroll
    for (int s = 0; s < 2; ++s) {
        const int rr = (2 * s + w) * 64 + lane;
#pragma unroll
        for (int q4 = 0; q4 < 4; ++q4) {
            float4 t = A4[rr * 4 + q4];
            x[s][q4*4+0] = t.x; x[s][q4*4+1] = t.y;
            x[s][q4*4+2] = t.z; x[s][q4*4+3] = t.w;
        }
    }

    // ---- G_bot via MFMA: 2 stages of 128 k-rows, both waves co-stage ----
    f32x4 accA = {0.f, 0.f, 0.f, 0.f};   // hh + ll chain
    f32x4 accB = {0.f, 0.f, 0.f, 0.f};   // hl + lh chain
    const int cm = lane & 15;
    const int g4 = lane >> 4;

#pragma unroll
    for (int t = 0; t < 2; ++t) {
        // write stage t: wave w's slot t = k-rows (2t+w)*64.. -> buffer row w*64+lane
#pragma unroll
        for (int c = 0; c < QC; ++c) {
            float v = x[t][c];
            if (t == 0 && w == 0) v = (lane < QC) ? 0.f : v;   // mask rows<16
            _Float16 hh = (_Float16)v;
            float     r = v - (float)hh;
            _Float16 ll = (_Float16)r;
            union { _Float16 f; unsigned short u; } ch, cl;
            ch.f = hh; cl.f = ll;
            hp[c * PITCH + w * 64 + lane] = ch.u;
            lp[c * PITCH + w * 64 + lane] = cl.u;
        }
        if (t == 1 && w == 0 && lane < QC) {
            // publish X_top (rows 0-15, original f32) for both waves' C build
#pragma unroll
            for (int c = 0; c < QC; ++c) xbuf[lane * 20 + c] = x[0][c];
        }
        __syncthreads();                   // writes visible before frag reads
#pragma unroll
        for (int h = 0; h < 4; ++h) {      // 4 K=32 chunks, ascending k (as r8)
            const int fi = cm * PITCH + 32 * h + 8 * g4;
            const half8 fh = *reinterpret_cast<const half8*>(&hp[fi]);
            const half8 fl = *reinterpret_cast<const half8*>(&lp[fi]);
            accA = __builtin_amdgcn_mfma_f32_16x16x32_f16(fh, fh, accA, 0, 0, 0);
            accB = __builtin_amdgcn_mfma_f32_16x16x32_f16(fh, fl, accB, 0, 0, 0);
            accB = __builtin_amdgcn_mfma_f32_16x16x32_f16(fl, fh, accB, 0, 0, 0);
            accA = __builtin_amdgcn_mfma_f32_16x16x32_f16(fl, fl, accA, 0, 0, 0);
        }
        __syncthreads();                   // frag reads done before overwrite
    }
    const f32x4 Gf = accA + accB;          // identical bits in both waves

    // ---- scatter G to f32 buffer (pitch 20), gather row (lane&15).
    //      Both waves write identical values to the same addresses: benign. ----
    asm volatile("" ::: "memory");
#pragma unroll
    for (int q = 0; q < 4; ++q) gbuf[(4 * g4 + q) * 20 + cm] = Gf[q];
    asm volatile("" ::: "memory");
    float g[QC];
#pragma unroll
    for (int k = 0; k < 4; ++k) {
        const f32x4 t = *reinterpret_cast<const f32x4*>(&gbuf[(lane & 15) * 20 + 4 * k]);
        g[4*k+0] = t[0]; g[4*k+1] = t[1]; g[4*k+2] = t[2]; g[4*k+3] = t[3];
    }

    const int li = lane - 16;   // cholesky row index for lanes 16..31

    // ---- Cholesky of G_bot (row i in lane 16+i; other lanes carry copies) ----
    float rs = 0.f;
#pragma unroll
    for (int k = 0; k < QC; ++k) {
        const float piv = rdlane(g[k], 16 + k);          // A^(k)[k][k]
        const float inv = __builtin_amdgcn_rcpf(piv);
        const float rsk = __builtin_amdgcn_rsqf(piv);
        rs = (li == k) ? rsk : rs;
        const float m = (li > k) ? g[k] * inv : 0.f;     // frozen rows -> no-op
#pragma unroll
        for (int j = k + 1; j < QC; ++j) {
            const float bj = rdlane(g[j], 16 + k);       // A^(k)[k][j] broadcast
            g[j] = fmaf(-m, bj, g[j]);
        }
    }

    // ---- X_top from LDS (published by wave 0; barrier above covers) ----
    float xtop[QC];
#pragma unroll
    for (int k = 0; k < 4; ++k) {
        const f32x4 t = *reinterpret_cast<const f32x4*>(&xbuf[(lane & 15) * 20 + 4 * k]);
        xtop[4*k+0] = t[0]; xtop[4*k+1] = t[1]; xtop[4*k+2] = t[2]; xtop[4*k+3] = t[3];
    }

    // ---- C = [X_top ; U] built in lanes 0..31, then MIRRORED into 32..63 ----
    float c[QC];
#pragma unroll
    for (int t = 0; t < QC; ++t) {
        const float ub = (li <= t && li >= 0) ? g[t] * rs : 0.f;
        c[t] = (lane < QC) ? xtop[t] : ub;
    }
    const int baddr = (lane & 31) << 2;   // bpermute: lanes 32-63 pull lanes 0-31
#pragma unroll
    for (int t = 0; t < QC; ++t)
        c[t] = __int_as_float(__builtin_amdgcn_ds_bpermute(baddr, __float_as_int(c[t])));

    const bool hi  = (lane >= 32);
    const int  row = lane & 31;           // mirrored row index

    // column norms^2 of C (== column norms of X), two per chain
    float nrm2[QC];
#pragma unroll
    for (int m = 0; m < QC; m += 2) {
        const float pc = hi ? c[m + 1] : c[m];
        const float2 ss = dual_sum32(pc * pc);
        nrm2[m] = ss.x; nrm2[m + 1] = ss.y;
    }

    // ---- Householder on C (32x16), paired trailing columns ----
#pragma unroll
    for (int j = 0; j < QC; ++j) {
        const float piv   = rdlane(c[j], j);
        const float nrm   = sqrtf(nrm2[j]);
        const float alpha = -copysignf(nrm, piv);            // LAPACK dlarfg sign
        const float vtv   = 2.f * (nrm2[j] - alpha * piv);   // ||v||^2, no cancel
        const float beta  = 2.f * __builtin_amdgcn_rcpf(vtv);
        const float v = (row < j) ? 0.f : ((row == j) ? piv - alpha : c[j]);
        int t = j + 1;
#pragma unroll
        for (; t + 1 < QC; t += 2) {
            const float pc = hi ? c[t + 1] : c[t];
            const float2 d = dual_sum32(v * pc);
            const float wb0 = beta * d.x;
            const float wb1 = beta * d.y;
            c[t]     = fmaf(-wb0, v, c[t]);
            c[t + 1] = fmaf(-wb1, v, c[t + 1]);
            const float rv0 = rdlane(c[t], j);               // R[j][t] frozen now
            const float rv1 = rdlane(c[t + 1], j);
            nrm2[t]     = fmaf(-rv0, rv0, nrm2[t]);
            nrm2[t + 1] = fmaf(-rv1, rv1, nrm2[t + 1]);
        }
        if (t < QC) {                                        // odd tail column
            const float d  = wave_sum32(v * c[t]);
            const float wb = beta * d;
            c[t] = fmaf(-wb, v, c[t]);
            const float rv = rdlane(c[t], j);
            nrm2[t] = fmaf(-rv, rv, nrm2[t]);
        }
        c[j] = (row == j) ? alpha : c[j];                    // R[j][j] (mirrored)
    }

    // ---- Q = X R^{-1}: forward elimination over this wave's 2 slots ----
#pragma unroll
    for (int k = 0; k < QC; ++k) {
        const float rkk = rdlane(c[k], k);
        const float ikk = __builtin_amdgcn_rcpf(rkk);
        x[0][k] *= ikk; x[1][k] *= ikk;
#pragma unroll
        for (int t = k + 1; t < QC; ++t) {
            const float r = rdlane(c[t], k);                 // R[k][t]
            x[0][t] = fmaf(-r, x[0][k], x[0][t]);
            x[1][t] = fmaf(-r, x[1][k], x[1][t]);
        }
    }

    // ---- store (terminal burst; all 4 float4 of a row adjacent - r10 lesson) ----
#pragma unroll
    for (int s = 0; s < 2; ++s) {
        const int rr = (2 * s + w) * 64 + lane;
#pragma unroll
        for (int q4 = 0; q4 < 4; ++q4) {
            O4[rr * 4 + q4] = make_float4(x[s][q4*4+0], x[s][q4*4+1],
                                          x[s][q4*4+2], x[s][q4*4+3]);
        }
    }
}

extern "C" void kernel_launch(void* const* d_in, const int* in_sizes, int n_in,
                              void* d_out, int out_size, void* d_ws, size_t ws_size,
                              hipStream_t stream) {
    const float* X = (const float*)d_in[0];
    float*       O = (float*)d_out;
    qr_pair_r11<<<BATCH, 128, 0, stream>>>(X, O);
}